// Round 6
// baseline (19354.362 us; speedup 1.0000x reference)
//
#include <hip/hip_runtime.h>
#include <hip/hip_bf16.h>
#include <stdint.h>

// ---------------------------------------------------------------------------
// 2-layer GRU (B=64,T=512,IN=256,H=1024) + FC, fp32 I/O.
// Persistent grid-cooperative kernel, 128 WGs (64/layer), 1-step layer skew.
// R6: per-XCD L2 staging. Per iteration:
//   copy (coherent L3 -> local-L2 staging, contiguous, each XCD reads the
//   4 unique planes exactly once) -> XCD-local barrier -> compute (A reads
//   staging with sc0-only = L2-hit) -> global arrival barrier.
// XCD identity from s_getreg(HW_REG_XCC_ID); per-XCD rank/count registered
// at startup via atomics (WG->XCD distribution is not guaranteed uniform).
// Compute is R5's counted-vmcnt asm pipeline (A now L2-latency).
// Precision: W bf16, h as bf16 hi+lo planes, gates fp32.
// ---------------------------------------------------------------------------

constexpr int TSEQ = 512;
constexpr int NB   = 64;
constexpr int HD   = 1024;
constexpr int IND  = 256;
constexpr int NWG  = 128;
constexpr int FS   = 16;            // counter stride in ints (64B lines)
constexpr int PL   = NB * HD;       // elements per plane (65536)

typedef float f32x4  __attribute__((ext_vector_type(4)));
typedef short short8 __attribute__((ext_vector_type(8)));

__device__ __forceinline__ float bf2f(unsigned u) {
    return __builtin_bit_cast(float, u << 16);
}
__device__ __forceinline__ unsigned short f2bf(float f) {
    unsigned u = __builtin_bit_cast(unsigned, f);
    u += 0x7fffu + ((u >> 16) & 1u);     // RNE
    return (unsigned short)(u >> 16);
}
__device__ __forceinline__ float sigm(float x) { return 1.0f / (1.0f + __expf(-x)); }
__device__ __forceinline__ float tanh_fast(float x) { return 1.0f - 2.0f / (1.0f + __expf(2.0f * x)); }

__device__ __forceinline__ unsigned short cload16(const unsigned short* p) {
    return __hip_atomic_load(p, __ATOMIC_RELAXED, __HIP_MEMORY_SCOPE_AGENT);
}
__device__ __forceinline__ void cstore16(unsigned short* p, unsigned short v) {
    __hip_atomic_store(p, v, __ATOMIC_RELAXED, __HIP_MEMORY_SCOPE_AGENT);
}

#define MFMA(a, b, c) __builtin_amdgcn_mfma_f32_16x16x32_bf16((a), (b), (c), 0, 0, 0)

// Coherent L3 load (copy phase), 16B.
#define LDC16(dst, ptr) \
    asm volatile("global_load_dwordx4 %0, %1, off sc0 sc1" : "=v"(dst) : "v"(ptr))
// XCD-local staged load: bypass L1, hit local L2.
#define LDB16(dst, base, imm) \
    asm volatile("global_load_dwordx4 %0, %1, off offset:%2 sc0" \
                 : "=v"(dst) : "v"(base), "i"(imm))
#define LDB16U(dst, ptr) \
    asm volatile("global_load_ushort %0, %1, off sc0" : "=v"(dst) : "v"(ptr))
// Cached W load (L2).
#define LDW16(dst, base, imm) \
    asm volatile("global_load_dwordx4 %0, %1, off offset:%2" \
                 : "=v"(dst) : "v"(base), "i"(imm))
#define VWAIT(n) do { asm volatile("s_waitcnt vmcnt(" #n ")" ::: "memory"); \
                      __builtin_amdgcn_sched_barrier(0); } while (0)
#define CFENCE() asm volatile("" ::: "memory")

__global__ void convert_w(const float* __restrict__ src, unsigned short* __restrict__ dst, int n) {
    int i = blockIdx.x * blockDim.x + threadIdx.x;
    int stride = gridDim.x * blockDim.x;
    for (; i < n; i += stride) dst[i] = f2bf(src[i]);
}

__global__ __launch_bounds__(256, 1) void gru_main(
    const float* __restrict__ x,
    const unsigned short* __restrict__ wih0,
    const unsigned short* __restrict__ whh0,
    const unsigned short* __restrict__ wih1,
    const unsigned short* __restrict__ whh1,
    const float* __restrict__ bih0, const float* __restrict__ bhh0,
    const float* __restrict__ bih1, const float* __restrict__ bhh1,
    const float* __restrict__ wfc,  const float* __restrict__ bfc,
    unsigned short* __restrict__ h0hi, unsigned short* __restrict__ h0lo,
    unsigned short* __restrict__ h1hi, unsigned short* __restrict__ h1lo,
    unsigned short* __restrict__ stg,
    int* __restrict__ arrive, int* __restrict__ larrive, int* __restrict__ xcnt,
    float* __restrict__ out)
{
    const int wg    = blockIdx.x;
    const int layer = wg >> 6;
    const int cc    = wg & 63;
    const int jb    = cc << 4;
    const int tid   = threadIdx.x;
    const int wave  = tid >> 6;
    const int lane  = tid & 63;
    const int l15   = lane & 15;
    const int kg8   = (lane >> 4) << 3;
    const int arow  = (wave << 4) + l15;

    const unsigned short* Whh = layer ? whh1 : whh0;
    const unsigned short* Wih = layer ? wih1 : wih0;
    const float* bih = layer ? bih1 : bih0;
    const float* bhh = layer ? bhh1 : bhh0;
    unsigned short* hhi = layer ? h1hi : h0hi;
    unsigned short* hlo = layer ? h1lo : h0lo;

    const int jg = jb + l15;
    const int KW = layer ? HD : IND;
    const unsigned short* bWR = Whh + (size_t)jg          * HD + kg8;
    const unsigned short* bWZ = Whh + (size_t)(HD   + jg) * HD + kg8;
    const unsigned short* bWN = Whh + (size_t)(2*HD + jg) * HD + kg8;
    const unsigned short* bIR = Wih + (size_t)jg          * KW + kg8;
    const unsigned short* bIZ = Wih + (size_t)(HD   + jg) * KW + kg8;
    const unsigned short* bIN = Wih + (size_t)(2*HD + jg) * KW + kg8;

    const float bias_r  = bih[jg]        + bhh[jg];
    const float bias_z  = bih[HD + jg]   + bhh[HD + jg];
    const float bias_nx = bih[2*HD + jg];
    const float bias_nh = bhh[2*HD + jg];

    // ---- XCD identity + per-XCD registration ----
    unsigned xcd;
    asm("s_getreg_b32 %0, hwreg(HW_REG_XCC_ID)" : "=s"(xcd));
    xcd &= 7;
    unsigned short* stx = stg + (size_t)xcd * 4 * PL;

    __shared__ int sh_rank, sh_ng;
    if (tid == 0) sh_rank = atomicAdd(&xcnt[xcd * FS], 1);
    __syncthreads();
    const int rank = sh_rank;
    // pre-loop global barrier (slot 0): all registrations visible
    if (tid == 0) {
        atomicAdd(&arrive[0], 1);
        int spins = 0;
        while (__hip_atomic_load(&arrive[0], __ATOMIC_RELAXED,
                                 __HIP_MEMORY_SCOPE_AGENT) < NWG) {
            __builtin_amdgcn_s_sleep(1);
            if (++spins > (1 << 20)) break;
        }
        sh_ng = __hip_atomic_load(&xcnt[xcd * FS], __ATOMIC_RELAXED,
                                  __HIP_MEMORY_SCOPE_AGENT);
    }
    __syncthreads();
    const int ng = sh_ng;
    const int slice = (8192 + ng - 1) / ng;   // 16B-chunks per plane per WG

    // Iteration-invariant staged A/pointwise pointers.
    // Staging planes: [0]=S0hi=h0(i-1).hi  [1]=S0lo  [2]=S1hi=h1(i-2).hi  [3]=S1lo
    const unsigned short *bAh, *bAl, *bAy = nullptr, *ph_hi, *ph_lo;
    if (layer == 0) {
        bAh = stx + 0 * PL + (size_t)arow * HD + kg8;
        bAl = stx + 1 * PL + (size_t)arow * HD + kg8;
        ph_hi = stx + 0 * PL;  ph_lo = stx + 1 * PL;
    } else {
        bAh = stx + 2 * PL + (size_t)arow * HD + kg8;
        bAl = stx + 3 * PL + (size_t)arow * HD + kg8;
        bAy = stx + 0 * PL + (size_t)arow * HD + kg8;
        ph_hi = stx + 2 * PL;  ph_lo = stx + 3 * PL;
    }

    for (int iter = 0; iter <= TSEQ; ++iter) {
        // ======== staging copy: coherent L3 -> local L2 (all WGs) ========
        {
            const unsigned short* csrc[4];
            csrc[0] = h0hi + ((iter + 1) & 1) * PL;
            csrc[1] = h0lo + ((iter + 1) & 1) * PL;
            csrc[2] = h1hi + (iter & 1) * PL;
            csrc[3] = h1lo + (iter & 1) * PL;
            const int p0 = rank * slice;
            const int p1 = (p0 + slice < 8192) ? (p0 + slice) : 8192;
            for (int jb2 = 0; jb2 < slice; jb2 += 512) {
                short8 v[8]; int qo[8];
                #pragma unroll
                for (int b = 0; b < 8; ++b) {
                    const int pl = b & 3;
                    int q = p0 + jb2 + ((b >> 2) << 8) + tid;
                    q = (q < p1) ? q : (p1 - 1);
                    qo[b] = pl * PL + q * 8;
                    LDC16(v[b], csrc[pl] + (size_t)q * 8);
                }
                VWAIT(0);
                #pragma unroll
                for (int b = 0; b < 8; ++b)
                    *(short8*)(stx + qo[b]) = v[b];
            }
        }
        asm volatile("s_waitcnt vmcnt(0)" ::: "memory");   // staging in L2
        __syncthreads();
        // ---- XCD-local barrier ----
        if (tid == 0) {
            atomicAdd(&larrive[(iter * 8 + (int)xcd) * FS], 1);
            int spins = 0;
            while (__hip_atomic_load(&larrive[(iter * 8 + (int)xcd) * FS],
                                     __ATOMIC_RELAXED, __HIP_MEMORY_SCOPE_AGENT) < ng) {
                __builtin_amdgcn_s_sleep(1);
                if (++spins > (1 << 20)) break;
            }
        }
        __syncthreads();

        // ======== compute ========
        const bool active = layer ? (iter >= 1) : (iter < TSEQ);
        if (active) {
            const int t     = layer ? (iter - 1) : iter;
            const int wslot = t & 1;

            f32x4 ar  = {0.f, 0.f, 0.f, 0.f};
            f32x4 az  = {0.f, 0.f, 0.f, 0.f};
            f32x4 ahn = {0.f, 0.f, 0.f, 0.f};
            f32x4 axn = {0.f, 0.f, 0.f, 0.f};

            // ptwise old-h (8 asm loads, oldest in vmcnt queue; absorbed by
            // the body-0 counted wait: L0 drains 8+5=13, L1 drains 8+9=17)
            unsigned hoh[4], hol[4];
            #pragma unroll
            for (int e = 0; e < 4; ++e) {
                const int bat = (wave << 4) + ((lane >> 4) << 2) + e;
                LDB16U(hoh[e], ph_hi + (size_t)bat * HD + jg);
                LDB16U(hol[e], ph_lo + (size_t)bat * HD + jg);
            }
            CFENCE();

            if (layer == 0) {
                short8 Wr[4][3];
                short8 Ah[5], Al[5];
#define L0A(c) do { LDB16(Ah[(c)%5], bAh, (c)*64); LDB16(Al[(c)%5], bAl, (c)*64); } while(0)
#define L0W(c) do { LDW16(Wr[(c)&3][0], bWR, (c)*64); LDW16(Wr[(c)&3][1], bWZ, (c)*64); \
                    LDW16(Wr[(c)&3][2], bWN, (c)*64); } while(0)
#define L0MF(c) do { \
    ar  = MFMA(Ah[(c)%5], Wr[(c)&3][0], ar);  ar  = MFMA(Al[(c)%5], Wr[(c)&3][0], ar);  \
    az  = MFMA(Ah[(c)%5], Wr[(c)&3][1], az);  az  = MFMA(Al[(c)%5], Wr[(c)&3][1], az);  \
    ahn = MFMA(Ah[(c)%5], Wr[(c)&3][2], ahn); ahn = MFMA(Al[(c)%5], Wr[(c)&3][2], ahn); } while(0)
#define L0S(c) do { L0W((c)+3); L0A((c)+4); VWAIT(17); L0MF(c); } while(0)
                L0A(0); L0W(0); L0A(1); L0W(1); L0A(2); L0W(2); L0A(3);
                L0S(0);  L0S(1);  L0S(2);  L0S(3);  L0S(4);  L0S(5);  L0S(6);
                L0S(7);  L0S(8);  L0S(9);  L0S(10); L0S(11); L0S(12); L0S(13);
                L0S(14); L0S(15); L0S(16); L0S(17); L0S(18); L0S(19); L0S(20);
                L0S(21); L0S(22); L0S(23); L0S(24); L0S(25); L0S(26); L0S(27);
                L0W(31); VWAIT(15); L0MF(28);
                VWAIT(10); L0MF(29);
                VWAIT(5);  L0MF(30);
                VWAIT(0);  L0MF(31);
                CFENCE();
                // input projection x @ W_ih (K=256): plain cached loads
                const float* px = x + ((size_t)arow * TSEQ + t) * IND + kg8;
                #pragma unroll
                for (int k = 0; k < 8; ++k) {
                    float4 xa = *(const float4*)(px + k * 32);
                    float4 xc = *(const float4*)(px + k * 32 + 4);
                    short8 af;
                    af[0] = (short)f2bf(xa.x); af[1] = (short)f2bf(xa.y);
                    af[2] = (short)f2bf(xa.z); af[3] = (short)f2bf(xa.w);
                    af[4] = (short)f2bf(xc.x); af[5] = (short)f2bf(xc.y);
                    af[6] = (short)f2bf(xc.z); af[7] = (short)f2bf(xc.w);
                    short8 br = *(const short8*)(bIR + k * 32);
                    short8 bz = *(const short8*)(bIZ + k * 32);
                    short8 bn = *(const short8*)(bIN + k * 32);
                    ar  = MFMA(af, br, ar);
                    az  = MFMA(af, bz, az);
                    axn = MFMA(af, bn, axn);
                }
            } else {
                short8 Wr[4][6];
                short8 Ah[5], Al[5], Ay[5];
#define L1A(c) do { LDB16(Ah[(c)%5], bAh, (c)*64); LDB16(Al[(c)%5], bAl, (c)*64); \
                    LDB16(Ay[(c)%5], bAy, (c)*64); } while(0)
#define L1W(c) do { LDW16(Wr[(c)&3][0], bWR, (c)*64); LDW16(Wr[(c)&3][1], bWZ, (c)*64); \
                    LDW16(Wr[(c)&3][2], bWN, (c)*64); LDW16(Wr[(c)&3][3], bIR, (c)*64); \
                    LDW16(Wr[(c)&3][4], bIZ, (c)*64); LDW16(Wr[(c)&3][5], bIN, (c)*64); } while(0)
#define L1MF(c) do { \
    ar  = MFMA(Ah[(c)%5], Wr[(c)&3][0], ar);  ar  = MFMA(Al[(c)%5], Wr[(c)&3][0], ar);  \
    ar  = MFMA(Ay[(c)%5], Wr[(c)&3][3], ar); \
    az  = MFMA(Ah[(c)%5], Wr[(c)&3][1], az);  az  = MFMA(Al[(c)%5], Wr[(c)&3][1], az);  \
    az  = MFMA(Ay[(c)%5], Wr[(c)&3][4], az); \
    ahn = MFMA(Ah[(c)%5], Wr[(c)&3][2], ahn); ahn = MFMA(Al[(c)%5], Wr[(c)&3][2], ahn); \
    axn = MFMA(Ay[(c)%5], Wr[(c)&3][5], axn); } while(0)
#define L1S(c) do { L1W((c)+3); L1A((c)+4); VWAIT(30); L1MF(c); } while(0)
                L1A(0); L1W(0); L1A(1); L1W(1); L1A(2); L1W(2); L1A(3);
                L1S(0);  L1S(1);  L1S(2);  L1S(3);  L1S(4);  L1S(5);  L1S(6);
                L1S(7);  L1S(8);  L1S(9);  L1S(10); L1S(11); L1S(12); L1S(13);
                L1S(14); L1S(15); L1S(16); L1S(17); L1S(18); L1S(19); L1S(20);
                L1S(21); L1S(22); L1S(23); L1S(24); L1S(25); L1S(26); L1S(27);
                L1W(31); VWAIT(27); L1MF(28);
                VWAIT(18); L1MF(29);
                VWAIT(9);  L1MF(30);
                VWAIT(0);  L1MF(31);
                CFENCE();
            }

            // ---- gates + state update + coherent (write-through) store ----
            unsigned short* hwhi = hhi + wslot * PL;
            unsigned short* hwlo = hlo + wslot * PL;
            #pragma unroll
            for (int e = 0; e < 4; ++e) {
                const int bat = (wave << 4) + ((lane >> 4) << 2) + e;
                const size_t idx = (size_t)bat * HD + jg;
                float r = sigm(ar[e] + bias_r);
                float z = sigm(az[e] + bias_z);
                float n = tanh_fast(axn[e] + bias_nx + r * (ahn[e] + bias_nh));
                float hold = bf2f(hoh[e]) + bf2f(hol[e]);
                float hnew = (1.0f - z) * n + z * hold;
                unsigned short hi_ = f2bf(hnew);
                cstore16(hwhi + idx, hi_);
                cstore16(hwlo + idx, f2bf(hnew - bf2f((unsigned)hi_)));
            }
        }

        // ---- global barrier ----
        asm volatile("s_waitcnt vmcnt(0)" ::: "memory");   // h stores at L3
        __syncthreads();
        if (tid == 0) {
            atomicAdd(&arrive[(iter + 1) * FS], 1);
            int spins = 0;
            while (__hip_atomic_load(&arrive[(iter + 1) * FS],
                                     __ATOMIC_RELAXED, __HIP_MEMORY_SCOPE_AGENT) < NWG) {
                __builtin_amdgcn_s_sleep(1);
                if (++spins > (1 << 20)) break;
            }
        }
        __syncthreads();
    }

    // ---- deterministic FC tail (single WG, coherent reads) ----
    if (wg == 64) {
        const int fslot = (TSEQ - 1) & 1;
        const unsigned short* hf_hi = h1hi + (size_t)fslot * PL;
        const unsigned short* hf_lo = h1lo + (size_t)fslot * PL;
        const int bat  = tid & 63;
        const int part = tid >> 6;
        const int k0   = part * (HD / 4);
        float s = 0.0f;
        for (int k = 0; k < HD / 4; ++k) {
            size_t idx = (size_t)bat * HD + k0 + k;
            s += (bf2f((unsigned)cload16(hf_hi + idx)) +
                  bf2f((unsigned)cload16(hf_lo + idx))) * wfc[k0 + k];
        }
        __shared__ float red[256];
        red[tid] = s;
        __syncthreads();
        if (tid < 64)
            out[tid] = red[tid] + red[tid + 64] + red[tid + 128] + red[tid + 192] + bfc[0];
    }
}

extern "C" void kernel_launch(void* const* d_in, const int* in_sizes, int n_in,
                              void* d_out, int out_size, void* d_ws, size_t ws_size,
                              hipStream_t stream) {
    const float* x    = (const float*)d_in[0];
    const float* Wih0 = (const float*)d_in[1];
    const float* Whh0 = (const float*)d_in[2];
    const float* bih0 = (const float*)d_in[3];
    const float* bhh0 = (const float*)d_in[4];
    const float* Wih1 = (const float*)d_in[5];
    const float* Whh1 = (const float*)d_in[6];
    const float* bih1 = (const float*)d_in[7];
    const float* bhh1 = (const float*)d_in[8];
    const float* Wfc  = (const float*)d_in[9];
    const float* bfc  = (const float*)d_in[10];
    float* out = (float*)d_out;

    char* ws = (char*)d_ws;
    size_t off = 0;
    int* arrive  = (int*)(ws + off); off += (size_t)(TSEQ + 2) * FS * 4;
    int* larrive = (int*)(ws + off); off += (size_t)(TSEQ + 1) * 8 * FS * 4;
    int* xcnt    = (int*)(ws + off); off += (size_t)8 * FS * 4;
    unsigned short* h0hi = (unsigned short*)(ws + off); off += (size_t)2 * PL * 2;
    unsigned short* h0lo = (unsigned short*)(ws + off); off += (size_t)2 * PL * 2;
    unsigned short* h1hi = (unsigned short*)(ws + off); off += (size_t)2 * PL * 2;
    unsigned short* h1lo = (unsigned short*)(ws + off); off += (size_t)2 * PL * 2;
    size_t zero_bytes = off;
    unsigned short* wih0b = (unsigned short*)(ws + off); off += (size_t)3 * HD * IND * 2;
    unsigned short* whh0b = (unsigned short*)(ws + off); off += (size_t)3 * HD * HD * 2;
    unsigned short* wih1b = (unsigned short*)(ws + off); off += (size_t)3 * HD * HD * 2;
    unsigned short* whh1b = (unsigned short*)(ws + off); off += (size_t)3 * HD * HD * 2;
    unsigned short* stg   = (unsigned short*)(ws + off); off += (size_t)8 * 4 * PL * 2;
    if (off > ws_size) return;   // loud validation failure

    hipMemsetAsync(d_ws, 0, zero_bytes, stream);
    hipMemsetAsync(d_out, 0, (size_t)out_size * sizeof(float), stream);

    convert_w<<<512, 256, 0, stream>>>(Wih0, wih0b, 3 * HD * IND);
    convert_w<<<512, 256, 0, stream>>>(Whh0, whh0b, 3 * HD * HD);
    convert_w<<<512, 256, 0, stream>>>(Wih1, wih1b, 3 * HD * HD);
    convert_w<<<512, 256, 0, stream>>>(Whh1, whh1b, 3 * HD * HD);

    gru_main<<<NWG, 256, 0, stream>>>(x, wih0b, whh0b, wih1b, whh1b,
                                      bih0, bhh0, bih1, bhh1, Wfc, bfc,
                                      h0hi, h0lo, h1hi, h1lo, stg,
                                      arrive, larrive, xcnt, out);
}

// Round 8
// 8661.195 us; speedup vs baseline: 2.2346x; 2.2346x over previous
//
#include <hip/hip_runtime.h>
#include <hip/hip_bf16.h>
#include <stdint.h>

// ---------------------------------------------------------------------------
// 2-layer GRU (B=64,T=512,IN=256,H=1024) + FC, fp32 I/O.
// R8: 256 WGs x 256 thr (1/CU). WG = (layer, K-half, 16-col chunk).
// W tile (98KB L1 / 60KB L0) staged into LDS ONCE; per-body W via ds_read.
// Per-iter VMEM per CU: A half-K planes only (~192KB) — attacks the measured
// ~35B/cy/CU VMEM wall (R5/R6 evidence). K-half partials combined via a
// coherent exchange buffer + per-pair flag handshake (kh1 -> kh0), then one
// flat global arrival barrier (R4/R5-proven). A-loads: counted-vmcnt asm
// rings (2-3 streams x ring-5, ~60 VGPR -> no spill risk; R7 lesson).
// Precision: W bf16, h as bf16 hi+lo planes, gates fp32 (absmax 3.7e-4 grade).
// ---------------------------------------------------------------------------

constexpr int TSEQ = 512;
constexpr int NB   = 64;
constexpr int HD   = 1024;
constexpr int IND  = 256;
constexpr int NWG  = 256;
constexpr int FS   = 16;            // counter stride in ints (64B lines)
constexpr int PL   = NB * HD;       // elements per h plane

typedef float f32x4  __attribute__((ext_vector_type(4)));
typedef short short8 __attribute__((ext_vector_type(8)));

__device__ __forceinline__ float bf2f(unsigned u) {
    return __builtin_bit_cast(float, u << 16);
}
__device__ __forceinline__ unsigned short f2bf(float f) {
    unsigned u = __builtin_bit_cast(unsigned, f);
    u += 0x7fffu + ((u >> 16) & 1u);     // RNE
    return (unsigned short)(u >> 16);
}
__device__ __forceinline__ float sigm(float x) { return 1.0f / (1.0f + __expf(-x)); }
__device__ __forceinline__ float tanh_fast(float x) { return 1.0f - 2.0f / (1.0f + __expf(2.0f * x)); }

__device__ __forceinline__ void cstore16(unsigned short* p, unsigned short v) {
    __hip_atomic_store(p, v, __ATOMIC_RELAXED, __HIP_MEMORY_SCOPE_AGENT);
}
__device__ __forceinline__ unsigned short cload16(const unsigned short* p) {
    return __hip_atomic_load(p, __ATOMIC_RELAXED, __HIP_MEMORY_SCOPE_AGENT);
}
__device__ __forceinline__ void cstoref(float* p, float v) {
    __hip_atomic_store(p, v, __ATOMIC_RELAXED, __HIP_MEMORY_SCOPE_AGENT);
}
__device__ __forceinline__ float cloadf(const float* p) {
    return __hip_atomic_load(p, __ATOMIC_RELAXED, __HIP_MEMORY_SCOPE_AGENT);
}

#define MFMA(a, b, c) __builtin_amdgcn_mfma_f32_16x16x32_bf16((a), (b), (c), 0, 0, 0)

// Coherent A-load (L3), 16B, immediate byte offset.
#define LDA16(dst, base, imm) \
    asm volatile("global_load_dwordx4 %0, %1, off offset:%2 sc0 sc1" \
                 : "=v"(dst) : "v"(base), "i"(imm))
// Plain cached 16B load (x input).
#define LDX16(dst, base, imm) \
    asm volatile("global_load_dwordx4 %0, %1, off offset:%2" \
                 : "=v"(dst) : "v"(base), "i"(imm))
#define VWAIT(n) do { asm volatile("s_waitcnt vmcnt(" #n ")" ::: "memory"); \
                      __builtin_amdgcn_sched_barrier(0); } while (0)

__global__ void convert_w(const float* __restrict__ src, unsigned short* __restrict__ dst, int n) {
    int i = blockIdx.x * blockDim.x + threadIdx.x;
    int stride = gridDim.x * blockDim.x;
    for (; i < n; i += stride) dst[i] = f2bf(src[i]);
}

__global__ __launch_bounds__(256, 1) void gru_main(
    const float* __restrict__ x,
    const unsigned short* __restrict__ wih0,
    const unsigned short* __restrict__ whh0,
    const unsigned short* __restrict__ wih1,
    const unsigned short* __restrict__ whh1,
    const float* __restrict__ bih0, const float* __restrict__ bhh0,
    const float* __restrict__ bih1, const float* __restrict__ bhh1,
    const float* __restrict__ wfc,  const float* __restrict__ bfc,
    unsigned short* __restrict__ h0hi, unsigned short* __restrict__ h0lo,
    unsigned short* __restrict__ h1hi, unsigned short* __restrict__ h1lo,
    float* __restrict__ pbuf, int* __restrict__ pflag, int* __restrict__ arrive,
    float* __restrict__ out)
{
    const int wg    = blockIdx.x;
    const int layer = wg >> 7;           // 0 / 1
    const int kh    = (wg >> 6) & 1;     // K-half
    const int cc    = wg & 63;           // 16-col chunk
    const int pair  = (layer << 6) | cc;
    const int jb    = cc << 4;
    const int tid   = threadIdx.x;
    const int wid   = tid >> 6;          // wave = M-tile
    const int lane  = tid & 63;
    const int l15   = lane & 15;
    const int kg8   = (lane >> 4) << 3;
    const int arow  = (wid << 4) + l15;
    const int kb    = kh << 9;           // recurrent K base (0 / 512)
    const int kbx   = kh << 7;           // L0 input K base (0 / 128)

    const unsigned short* Whh = layer ? whh1 : whh0;
    const unsigned short* Wih = layer ? wih1 : wih0;
    const float* bih = layer ? bih1 : bih0;
    const float* bhh = layer ? bhh1 : bhh0;
    unsigned short* hhi = layer ? h1hi : h0hi;
    unsigned short* hlo = layer ? h1lo : h0lo;

    const int jg = jb + l15;
    const int KW = layer ? HD : IND;
    const int kbi = layer ? kb : kbx;
    const unsigned short* bWR = Whh + (size_t)jg          * HD + kb + kg8;
    const unsigned short* bWZ = Whh + (size_t)(HD   + jg) * HD + kb + kg8;
    const unsigned short* bWN = Whh + (size_t)(2*HD + jg) * HD + kb + kg8;
    const unsigned short* bIR = Wih + (size_t)jg          * KW + kbi + kg8;
    const unsigned short* bIZ = Wih + (size_t)(HD   + jg) * KW + kbi + kg8;
    const unsigned short* bIN = Wih + (size_t)(2*HD + jg) * KW + kbi + kg8;

    const float bias_r  = bih[jg]        + bhh[jg];
    const float bias_z  = bih[HD + jg]   + bhh[HD + jg];
    const float bias_nx = bih[2*HD + jg];
    const float bias_nh = bhh[2*HD + jg];

    __shared__ unsigned short wlds[96 * 512];   // 96 x 1KB fragment blocks
    __shared__ float red[256];

    // ---- one-time W staging into LDS (wave 0; layout = per-lane 16B frags) ----
    if (wid == 0) {
        if (layer == 0) {
            const unsigned short* gh[3] = {bWR, bWZ, bWN};
            for (int s = 0; s < 3; ++s)
                for (int b = 0; b < 16; ++b)
                    *(short8*)(wlds + (s * 16 + b) * 512 + lane * 8) =
                        *(const short8*)(gh[s] + b * 32);
            const unsigned short* gi[3] = {bIR, bIZ, bIN};
            for (int s = 0; s < 3; ++s)
                for (int b = 0; b < 4; ++b)
                    *(short8*)(wlds + (48 + s * 4 + b) * 512 + lane * 8) =
                        *(const short8*)(gi[s] + b * 32);
        } else {
            const unsigned short* g6[6] = {bWR, bWZ, bWN, bIR, bIZ, bIN};
            for (int s = 0; s < 6; ++s)
                for (int b = 0; b < 16; ++b)
                    *(short8*)(wlds + (s * 16 + b) * 512 + lane * 8) =
                        *(const short8*)(g6[s] + b * 32);
        }
    }
    __syncthreads();

#define LW(blk) (*(const short8*)(wlds + (blk) * 512 + lane * 8))

    float* pb = pbuf + (size_t)pair * (16 * 256) + (wid << 6) + lane;
    float hold[4] = {0.f, 0.f, 0.f, 0.f};

    for (int iter = 0; iter <= TSEQ; ++iter) {
        const bool active = layer ? (iter >= 1) : (iter < TSEQ);
        if (active) {
            const int t     = layer ? (iter - 1) : iter;
            const int rs    = (t + 1) & 1;
            const int wslot = t & 1;
            const unsigned short* hrhi = hhi + rs * PL;
            const unsigned short* hrlo = hlo + rs * PL;
            const unsigned short* bAh = hrhi + (size_t)arow * HD + kb + kg8;
            const unsigned short* bAl = hrlo + (size_t)arow * HD + kb + kg8;

            f32x4 ar  = {0.f, 0.f, 0.f, 0.f};
            f32x4 az  = {0.f, 0.f, 0.f, 0.f};
            f32x4 ahn = {0.f, 0.f, 0.f, 0.f};
            f32x4 axn = {0.f, 0.f, 0.f, 0.f};

            if (layer == 0) {
                const float* px = x + ((size_t)arow * TSEQ + t) * IND + kbx + kg8;
                short8 Ah[5], Al[5], Wa[3], Wb[3];
#define L0A(c) do { LDA16(Ah[(c)%5], bAh, (c)*64); LDA16(Al[(c)%5], bAl, (c)*64); } while (0)
#define L0X(c) do { LDX16(Ah[(c)%5], px, ((c)-16)*128); LDX16(Al[(c)%5], px, ((c)-16)*128+16); } while (0)
#define WPRE0(c, WB) do { \
    if ((c) < 16) { WB[0] = LW(c); WB[1] = LW(16 + (c)); WB[2] = LW(32 + (c)); } \
    else { WB[0] = LW(48 + (c) - 16); WB[1] = LW(52 + (c) - 16); WB[2] = LW(56 + (c) - 16); } } while (0)
#define MR0(c, WB) do { \
    ar  = MFMA(Ah[(c)%5], WB[0], ar);  ar  = MFMA(Al[(c)%5], WB[0], ar);  \
    az  = MFMA(Ah[(c)%5], WB[1], az);  az  = MFMA(Al[(c)%5], WB[1], az);  \
    ahn = MFMA(Ah[(c)%5], WB[2], ahn); ahn = MFMA(Al[(c)%5], WB[2], ahn); } while (0)
#define MX0(c, WB) do { \
    float4 xa = __builtin_bit_cast(float4, Ah[(c)%5]); \
    float4 xc = __builtin_bit_cast(float4, Al[(c)%5]); \
    short8 af; \
    af[0] = (short)f2bf(xa.x); af[1] = (short)f2bf(xa.y); \
    af[2] = (short)f2bf(xa.z); af[3] = (short)f2bf(xa.w); \
    af[4] = (short)f2bf(xc.x); af[5] = (short)f2bf(xc.y); \
    af[6] = (short)f2bf(xc.z); af[7] = (short)f2bf(xc.w); \
    ar  = MFMA(af, WB[0], ar); \
    az  = MFMA(af, WB[1], az); \
    axn = MFMA(af, WB[2], axn); } while (0)
                WPRE0(0, Wa);
                L0A(0); L0A(1); L0A(2); L0A(3);
                WPRE0(1,  Wb); L0A(4);  VWAIT(8); MR0(0,  Wa);
                WPRE0(2,  Wa); L0A(5);  VWAIT(8); MR0(1,  Wb);
                WPRE0(3,  Wb); L0A(6);  VWAIT(8); MR0(2,  Wa);
                WPRE0(4,  Wa); L0A(7);  VWAIT(8); MR0(3,  Wb);
                WPRE0(5,  Wb); L0A(8);  VWAIT(8); MR0(4,  Wa);
                WPRE0(6,  Wa); L0A(9);  VWAIT(8); MR0(5,  Wb);
                WPRE0(7,  Wb); L0A(10); VWAIT(8); MR0(6,  Wa);
                WPRE0(8,  Wa); L0A(11); VWAIT(8); MR0(7,  Wb);
                WPRE0(9,  Wb); L0A(12); VWAIT(8); MR0(8,  Wa);
                WPRE0(10, Wa); L0A(13); VWAIT(8); MR0(9,  Wb);
                WPRE0(11, Wb); L0A(14); VWAIT(8); MR0(10, Wa);
                WPRE0(12, Wa); L0A(15); VWAIT(8); MR0(11, Wb);
                WPRE0(13, Wb); L0X(16); VWAIT(8); MR0(12, Wa);
                WPRE0(14, Wa); L0X(17); VWAIT(8); MR0(13, Wb);
                WPRE0(15, Wb); L0X(18); VWAIT(8); MR0(14, Wa);
                WPRE0(16, Wa); L0X(19); VWAIT(8); MR0(15, Wb);
                WPRE0(17, Wb); VWAIT(6); MX0(16, Wa);
                WPRE0(18, Wa); VWAIT(4); MX0(17, Wb);
                WPRE0(19, Wb); VWAIT(2); MX0(18, Wa);
                               VWAIT(0); MX0(19, Wb);
            } else {
                const unsigned short* bAy = h0hi + (size_t)wslot * PL
                                                 + (size_t)arow * HD + kb + kg8;
                short8 Ah[5], Al[5], Ay[5], Wa[6], Wb[6];
#define L1A(c) do { LDA16(Ah[(c)%5], bAh, (c)*64); LDA16(Al[(c)%5], bAl, (c)*64); \
                    LDA16(Ay[(c)%5], bAy, (c)*64); } while (0)
#define WPRE1(c, WB) do { WB[0] = LW(c); WB[1] = LW(16 + (c)); WB[2] = LW(32 + (c)); \
    WB[3] = LW(48 + (c)); WB[4] = LW(64 + (c)); WB[5] = LW(80 + (c)); } while (0)
#define MF1(c, WB) do { \
    ar  = MFMA(Ah[(c)%5], WB[0], ar);  ar  = MFMA(Al[(c)%5], WB[0], ar);  \
    ar  = MFMA(Ay[(c)%5], WB[3], ar); \
    az  = MFMA(Ah[(c)%5], WB[1], az);  az  = MFMA(Al[(c)%5], WB[1], az);  \
    az  = MFMA(Ay[(c)%5], WB[4], az); \
    ahn = MFMA(Ah[(c)%5], WB[2], ahn); ahn = MFMA(Al[(c)%5], WB[2], ahn); \
    axn = MFMA(Ay[(c)%5], WB[5], axn); } while (0)
                WPRE1(0, Wa);
                L1A(0); L1A(1); L1A(2); L1A(3);
                WPRE1(1,  Wb); L1A(4);  VWAIT(12); MF1(0,  Wa);
                WPRE1(2,  Wa); L1A(5);  VWAIT(12); MF1(1,  Wb);
                WPRE1(3,  Wb); L1A(6);  VWAIT(12); MF1(2,  Wa);
                WPRE1(4,  Wa); L1A(7);  VWAIT(12); MF1(3,  Wb);
                WPRE1(5,  Wb); L1A(8);  VWAIT(12); MF1(4,  Wa);
                WPRE1(6,  Wa); L1A(9);  VWAIT(12); MF1(5,  Wb);
                WPRE1(7,  Wb); L1A(10); VWAIT(12); MF1(6,  Wa);
                WPRE1(8,  Wa); L1A(11); VWAIT(12); MF1(7,  Wb);
                WPRE1(9,  Wb); L1A(12); VWAIT(12); MF1(8,  Wa);
                WPRE1(10, Wa); L1A(13); VWAIT(12); MF1(9,  Wb);
                WPRE1(11, Wb); L1A(14); VWAIT(12); MF1(10, Wa);
                WPRE1(12, Wa); L1A(15); VWAIT(12); MF1(11, Wb);
                WPRE1(13, Wb); VWAIT(9); MF1(12, Wa);
                WPRE1(14, Wa); VWAIT(6); MF1(13, Wb);
                WPRE1(15, Wb); VWAIT(3); MF1(14, Wa);
                               VWAIT(0); MF1(15, Wb);
            }

            // ---- K-half combine via coherent exchange + pair flag ----
            int* fp = pflag + ((size_t)iter * 128 + pair) * FS;
            if (kh) {
                // producer: store raw partials, drain, set flag
                #pragma unroll
                for (int e = 0; e < 4; ++e) {
                    cstoref(pb + (0 * 4 + e) * 256, ar[e]);
                    cstoref(pb + (1 * 4 + e) * 256, az[e]);
                    cstoref(pb + (2 * 4 + e) * 256, ahn[e]);
                    cstoref(pb + (3 * 4 + e) * 256, axn[e]);
                }
                asm volatile("s_waitcnt vmcnt(0)" ::: "memory");
                __hip_atomic_store(fp, 1, __ATOMIC_RELAXED, __HIP_MEMORY_SCOPE_AGENT);
            } else {
                // consumer: wait flag, add partner partials, gate, store h
                if (tid == 0) {
                    int spins = 0;
                    while (__hip_atomic_load(fp, __ATOMIC_RELAXED,
                                             __HIP_MEMORY_SCOPE_AGENT) < 1) {
                        __builtin_amdgcn_s_sleep(1);
                        if (++spins > (1 << 20)) break;   // fail loud, never hang
                    }
                }
                __syncthreads();
                unsigned short* hwhi = hhi + wslot * PL;
                unsigned short* hwlo = hlo + wslot * PL;
                #pragma unroll
                for (int e = 0; e < 4; ++e) {
                    const float arr = ar[e]  + cloadf(pb + (0 * 4 + e) * 256);
                    const float azz = az[e]  + cloadf(pb + (1 * 4 + e) * 256);
                    const float ahh = ahn[e] + cloadf(pb + (2 * 4 + e) * 256);
                    const float axx = axn[e] + cloadf(pb + (3 * 4 + e) * 256);
                    const int bat = (wid << 4) + ((lane >> 4) << 2) + e;
                    const size_t idx = (size_t)bat * HD + jg;
                    float r = sigm(arr + bias_r);
                    float z = sigm(azz + bias_z);
                    float n = tanh_fast(axx + bias_nx + r * (ahh + bias_nh));
                    float hnew = (1.0f - z) * n + z * hold[e];
                    hold[e] = hnew;
                    unsigned short hi_ = f2bf(hnew);
                    cstore16(hwhi + idx, hi_);
                    cstore16(hwlo + idx, f2bf(hnew - bf2f((unsigned)hi_)));
                }
            }
        }

        // ---- flat global barrier (drain stores first) ----
        asm volatile("s_waitcnt vmcnt(0)" ::: "memory");
        __syncthreads();
        if (tid == 0) {
            atomicAdd(&arrive[(size_t)iter * FS], 1);
            int spins = 0;
            while (__hip_atomic_load(&arrive[(size_t)iter * FS],
                                     __ATOMIC_RELAXED, __HIP_MEMORY_SCOPE_AGENT) < NWG) {
                __builtin_amdgcn_s_sleep(1);
                if (++spins > (1 << 20)) break;
            }
        }
        __syncthreads();
    }

    // ---- deterministic FC tail (single WG, coherent reads) ----
    if (wg == 0) {
        const int fslot = (TSEQ - 1) & 1;
        const unsigned short* hf_hi = h1hi + (size_t)fslot * PL;
        const unsigned short* hf_lo = h1lo + (size_t)fslot * PL;
        const int bat  = tid & 63;
        const int part = tid >> 6;
        const int k0   = part * (HD / 4);
        float s = 0.0f;
        for (int k = 0; k < HD / 4; ++k) {
            size_t idx = (size_t)bat * HD + k0 + k;
            s += (bf2f((unsigned)cload16(hf_hi + idx)) +
                  bf2f((unsigned)cload16(hf_lo + idx))) * wfc[k0 + k];
        }
        red[tid] = s;
        __syncthreads();
        if (tid < 64)
            out[tid] = red[tid] + red[tid + 64] + red[tid + 128] + red[tid + 192] + bfc[0];
    }
}

extern "C" void kernel_launch(void* const* d_in, const int* in_sizes, int n_in,
                              void* d_out, int out_size, void* d_ws, size_t ws_size,
                              hipStream_t stream) {
    const float* x    = (const float*)d_in[0];
    const float* Wih0 = (const float*)d_in[1];
    const float* Whh0 = (const float*)d_in[2];
    const float* bih0 = (const float*)d_in[3];
    const float* bhh0 = (const float*)d_in[4];
    const float* Wih1 = (const float*)d_in[5];
    const float* Whh1 = (const float*)d_in[6];
    const float* bih1 = (const float*)d_in[7];
    const float* bhh1 = (const float*)d_in[8];
    const float* Wfc  = (const float*)d_in[9];
    const float* bfc  = (const float*)d_in[10];
    float* out = (float*)d_out;

    char* ws = (char*)d_ws;
    size_t off = 0;
    int* arrive = (int*)(ws + off);               off += (size_t)(TSEQ + 1) * FS * 4;
    int* pflag  = (int*)(ws + off);               off += (size_t)(TSEQ + 1) * 128 * FS * 4;
    unsigned short* h0hi = (unsigned short*)(ws + off); off += (size_t)2 * PL * 2;
    unsigned short* h0lo = (unsigned short*)(ws + off); off += (size_t)2 * PL * 2;
    unsigned short* h1hi = (unsigned short*)(ws + off); off += (size_t)2 * PL * 2;
    unsigned short* h1lo = (unsigned short*)(ws + off); off += (size_t)2 * PL * 2;
    size_t zero_bytes = off;
    float* pbuf = (float*)(ws + off);             off += (size_t)128 * 16 * 256 * 4;
    unsigned short* wih0b = (unsigned short*)(ws + off); off += (size_t)3 * HD * IND * 2;
    unsigned short* whh0b = (unsigned short*)(ws + off); off += (size_t)3 * HD * HD * 2;
    unsigned short* wih1b = (unsigned short*)(ws + off); off += (size_t)3 * HD * HD * 2;
    unsigned short* whh1b = (unsigned short*)(ws + off); off += (size_t)3 * HD * HD * 2;
    if (off > ws_size) return;   // loud validation failure

    hipMemsetAsync(d_ws, 0, zero_bytes, stream);
    hipMemsetAsync(d_out, 0, (size_t)out_size * sizeof(float), stream);

    convert_w<<<512, 256, 0, stream>>>(Wih0, wih0b, 3 * HD * IND);
    convert_w<<<512, 256, 0, stream>>>(Whh0, whh0b, 3 * HD * HD);
    convert_w<<<512, 256, 0, stream>>>(Wih1, wih1b, 3 * HD * HD);
    convert_w<<<512, 256, 0, stream>>>(Whh1, whh1b, 3 * HD * HD);

    gru_main<<<NWG, 256, 0, stream>>>(x, wih0b, whh0b, wih1b, whh1b,
                                      bih0, bhh0, bih1, bhh1, Wfc, bfc,
                                      h0hi, h0lo, h1hi, h1lo,
                                      pbuf, pflag, arrive, out);
}

// Round 9
// 8585.995 us; speedup vs baseline: 2.2542x; 1.0088x over previous
//
#include <hip/hip_runtime.h>
#include <hip/hip_bf16.h>
#include <stdint.h>

// ---------------------------------------------------------------------------
// 2-layer GRU (B=64,T=512,IN=256,H=1024) + FC, fp32 I/O.
// R9: 256 WGs x 512 thr. WG = (layer, 8-col chunk). 8 waves = 4 M-tiles x
// 2 K-halves; K-half partials combined in LDS (no cross-WG exchange, no
// pbuf/pflag HBM round trips — R8's measured 2.6MB/iter write overhead).
// Full-K W staged in LDS once (96KB, conflict-free [hi][col] frag layout;
// B-frag lanes 8-15 duplicate cols 0-7 — wasted MFMA lanes are cheap).
// A-loads: R8-proven counted-vmcnt asm rings. Flat arrival barrier (R8).
// Precision: W bf16, h as bf16 hi+lo planes, gates fp32.
// ---------------------------------------------------------------------------

constexpr int TSEQ = 512;
constexpr int NB   = 64;
constexpr int HD   = 1024;
constexpr int IND  = 256;
constexpr int NWG  = 256;
constexpr int FS   = 16;            // counter stride in ints (64B lines)
constexpr int PL   = NB * HD;       // elements per h plane

typedef float f32x4  __attribute__((ext_vector_type(4)));
typedef short short8 __attribute__((ext_vector_type(8)));

__device__ __forceinline__ float bf2f(unsigned u) {
    return __builtin_bit_cast(float, u << 16);
}
__device__ __forceinline__ unsigned short f2bf(float f) {
    unsigned u = __builtin_bit_cast(unsigned, f);
    u += 0x7fffu + ((u >> 16) & 1u);     // RNE
    return (unsigned short)(u >> 16);
}
__device__ __forceinline__ float sigm(float x) { return 1.0f / (1.0f + __expf(-x)); }
__device__ __forceinline__ float tanh_fast(float x) { return 1.0f - 2.0f / (1.0f + __expf(2.0f * x)); }

__device__ __forceinline__ void cstore16(unsigned short* p, unsigned short v) {
    __hip_atomic_store(p, v, __ATOMIC_RELAXED, __HIP_MEMORY_SCOPE_AGENT);
}
__device__ __forceinline__ unsigned short cload16(const unsigned short* p) {
    return __hip_atomic_load(p, __ATOMIC_RELAXED, __HIP_MEMORY_SCOPE_AGENT);
}

#define MFMA(a, b, c) __builtin_amdgcn_mfma_f32_16x16x32_bf16((a), (b), (c), 0, 0, 0)

// Coherent A-load (L3), 16B, immediate byte offset.
#define LDA16(dst, base, imm) \
    asm volatile("global_load_dwordx4 %0, %1, off offset:%2 sc0 sc1" \
                 : "=v"(dst) : "v"(base), "i"(imm))
// Plain cached 16B load (x input).
#define LDX16(dst, base, imm) \
    asm volatile("global_load_dwordx4 %0, %1, off offset:%2" \
                 : "=v"(dst) : "v"(base), "i"(imm))
#define VWAIT(n) do { asm volatile("s_waitcnt vmcnt(" #n ")" ::: "memory"); \
                      __builtin_amdgcn_sched_barrier(0); } while (0)

__global__ void convert_w(const float* __restrict__ src, unsigned short* __restrict__ dst, int n) {
    int i = blockIdx.x * blockDim.x + threadIdx.x;
    int stride = gridDim.x * blockDim.x;
    for (; i < n; i += stride) dst[i] = f2bf(src[i]);
}

__global__ __launch_bounds__(512, 2) void gru_main(
    const float* __restrict__ x,
    const unsigned short* __restrict__ wih0,
    const unsigned short* __restrict__ whh0,
    const unsigned short* __restrict__ wih1,
    const unsigned short* __restrict__ whh1,
    const float* __restrict__ bih0, const float* __restrict__ bhh0,
    const float* __restrict__ bih1, const float* __restrict__ bhh1,
    const float* __restrict__ wfc,  const float* __restrict__ bfc,
    unsigned short* __restrict__ h0hi, unsigned short* __restrict__ h0lo,
    unsigned short* __restrict__ h1hi, unsigned short* __restrict__ h1lo,
    int* __restrict__ arrive,
    float* __restrict__ out)
{
    const int wg    = blockIdx.x;
    const int layer = wg >> 7;           // 0 / 1
    const int cc    = wg & 127;          // 8-col chunk
    const int jb8   = cc << 3;
    const int tid   = threadIdx.x;
    const int wid   = tid >> 6;          // 0..7
    const int kh    = wid >> 2;          // K-half
    const int mw    = wid & 3;           // M-tile
    const int lane  = tid & 63;
    const int l15   = lane & 15;
    const int c8    = l15 & 7;           // real col within chunk (lanes 8-15 dup)
    const int kg8   = (lane >> 4) << 3;
    const int arow  = (mw << 4) + l15;
    const int kb    = kh << 9;           // recurrent K base (elements)
    const int ckb   = kh << 4;           // k-chunk base (chunks of 32)
    const int kbx   = kh << 7;           // L0 input K base

    const unsigned short* Whh = layer ? whh1 : whh0;
    const unsigned short* Wih = layer ? wih1 : wih0;
    const float* bih = layer ? bih1 : bih0;
    const float* bhh = layer ? bhh1 : bhh0;
    unsigned short* hhi = layer ? h1hi : h0hi;
    unsigned short* hlo = layer ? h1lo : h0lo;

    const int jg = jb8 + c8;

    const float bias_r  = bih[jg]        + bhh[jg];
    const float bias_z  = bih[HD + jg]   + bhh[HD + jg];
    const float bias_nx = bih[2*HD + jg];
    const float bias_nh = bhh[2*HD + jg];

    // W LDS: blocks of 512B = one k-chunk(32) x 8 cols; frag = [hi(4)][col(8)]x16B.
    // L1: blocks (s*32 + ck), s=0..5 {hhR,hhZ,hhN,ihR,ihZ,ihN}, ck=0..31.
    // L0: hh s=0..2 blocks (s*32+ck); ih blocks 96 + s*8 + ck (ck=0..7).
    __shared__ unsigned short wlds[192 * 256];   // 96KB
    __shared__ float part[16 * 4 * 64];          // 16KB K-half exchange
    __shared__ float red[256];

    if (layer == 1) {
        #pragma unroll
        for (int i = 0; i < 12; ++i) {
            int f = tid + i * 512;              // 0..6143
            int s   = f >> 10;
            int rem = f & 1023;
            int ck  = rem >> 5;
            int hi  = (rem >> 3) & 3;
            int c   = rem & 7;
            const unsigned short* src = (s < 3 ? Whh : Wih)
                + (size_t)((s % 3) * HD + jb8 + c) * HD + ck * 32 + hi * 8;
            *(short8*)(wlds + (s * 32 + ck) * 256 + hi * 64 + c * 8) =
                *(const short8*)src;
        }
    } else {
        #pragma unroll
        for (int i = 0; i < 6; ++i) {
            int f = tid + i * 512;              // 0..3071 (hh)
            int s   = f >> 10;
            int rem = f & 1023;
            int ck  = rem >> 5;
            int hi  = (rem >> 3) & 3;
            int c   = rem & 7;
            const unsigned short* src = Whh
                + (size_t)(s * HD + jb8 + c) * HD + ck * 32 + hi * 8;
            *(short8*)(wlds + (s * 32 + ck) * 256 + hi * 64 + c * 8) =
                *(const short8*)src;
        }
        for (int i = 0; i < 2; ++i) {
            int f = tid + i * 512;              // 0..767 (ih)
            if (f < 768) {
                int s   = f >> 8;
                int rem = f & 255;
                int ck  = rem >> 5;
                int hi  = (rem >> 3) & 3;
                int c   = rem & 7;
                const unsigned short* src = Wih
                    + (size_t)(s * HD + jb8 + c) * IND + ck * 32 + hi * 8;
                *(short8*)(wlds + (96 + s * 8 + ck) * 256 + hi * 64 + c * 8) =
                    *(const short8*)src;
            }
        }
    }
    __syncthreads();

    const int lws = (lane >> 4) * 64 + c8 * 8;   // lane's frag offset in a block
#define LW(blk) (*(const short8*)(wlds + (blk) * 256 + lws))

    float hold[4] = {0.f, 0.f, 0.f, 0.f};   // kh0 threads' h cells (exact fp32)

    for (int iter = 0; iter <= TSEQ; ++iter) {
        const bool active = layer ? (iter >= 1) : (iter < TSEQ);
        if (active) {
            const int t     = layer ? (iter - 1) : iter;
            const int rs    = (t + 1) & 1;
            const int wslot = t & 1;
            const unsigned short* hrhi = hhi + rs * PL;
            const unsigned short* hrlo = hlo + rs * PL;
            const unsigned short* bAh = hrhi + (size_t)arow * HD + kb + kg8;
            const unsigned short* bAl = hrlo + (size_t)arow * HD + kb + kg8;

            f32x4 ar  = {0.f, 0.f, 0.f, 0.f};
            f32x4 az  = {0.f, 0.f, 0.f, 0.f};
            f32x4 ahn = {0.f, 0.f, 0.f, 0.f};
            f32x4 axn = {0.f, 0.f, 0.f, 0.f};

            if (layer == 0) {
                const float* px = x + ((size_t)arow * TSEQ + t) * IND + kbx + kg8;
                short8 Ah[5], Al[5], Wa[3], Wb[3];
#define L0A(c) do { LDA16(Ah[(c)%5], bAh, (c)*64); LDA16(Al[(c)%5], bAl, (c)*64); } while (0)
#define L0X(c) do { LDX16(Ah[(c)%5], px, ((c)-16)*128); LDX16(Al[(c)%5], px, ((c)-16)*128+16); } while (0)
#define WR0(c, WB) do { WB[0] = LW(ckb + (c)); WB[1] = LW(32 + ckb + (c)); \
                        WB[2] = LW(64 + ckb + (c)); } while (0)
#define WX0(c, WB) do { int xck = (ckb >> 2) + (c) - 16; \
                        WB[0] = LW(96 + xck); WB[1] = LW(104 + xck); \
                        WB[2] = LW(112 + xck); } while (0)
#define MR0(c, WB) do { \
    ar  = MFMA(Ah[(c)%5], WB[0], ar);  ar  = MFMA(Al[(c)%5], WB[0], ar);  \
    az  = MFMA(Ah[(c)%5], WB[1], az);  az  = MFMA(Al[(c)%5], WB[1], az);  \
    ahn = MFMA(Ah[(c)%5], WB[2], ahn); ahn = MFMA(Al[(c)%5], WB[2], ahn); } while (0)
#define MX0(c, WB) do { \
    float4 xa = __builtin_bit_cast(float4, Ah[(c)%5]); \
    float4 xc = __builtin_bit_cast(float4, Al[(c)%5]); \
    short8 af; \
    af[0] = (short)f2bf(xa.x); af[1] = (short)f2bf(xa.y); \
    af[2] = (short)f2bf(xa.z); af[3] = (short)f2bf(xa.w); \
    af[4] = (short)f2bf(xc.x); af[5] = (short)f2bf(xc.y); \
    af[6] = (short)f2bf(xc.z); af[7] = (short)f2bf(xc.w); \
    ar  = MFMA(af, WB[0], ar); \
    az  = MFMA(af, WB[1], az); \
    axn = MFMA(af, WB[2], axn); } while (0)
                WR0(0, Wa);
                L0A(0); L0A(1); L0A(2); L0A(3);
                WR0(1,  Wb); L0A(4);  VWAIT(8); MR0(0,  Wa);
                WR0(2,  Wa); L0A(5);  VWAIT(8); MR0(1,  Wb);
                WR0(3,  Wb); L0A(6);  VWAIT(8); MR0(2,  Wa);
                WR0(4,  Wa); L0A(7);  VWAIT(8); MR0(3,  Wb);
                WR0(5,  Wb); L0A(8);  VWAIT(8); MR0(4,  Wa);
                WR0(6,  Wa); L0A(9);  VWAIT(8); MR0(5,  Wb);
                WR0(7,  Wb); L0A(10); VWAIT(8); MR0(6,  Wa);
                WR0(8,  Wa); L0A(11); VWAIT(8); MR0(7,  Wb);
                WR0(9,  Wb); L0A(12); VWAIT(8); MR0(8,  Wa);
                WR0(10, Wa); L0A(13); VWAIT(8); MR0(9,  Wb);
                WR0(11, Wb); L0A(14); VWAIT(8); MR0(10, Wa);
                WR0(12, Wa); L0A(15); VWAIT(8); MR0(11, Wb);
                WR0(13, Wb); L0X(16); VWAIT(8); MR0(12, Wa);
                WR0(14, Wa); L0X(17); VWAIT(8); MR0(13, Wb);
                WR0(15, Wb); L0X(18); VWAIT(8); MR0(14, Wa);
                WX0(16, Wa); L0X(19); VWAIT(8); MR0(15, Wb);
                WX0(17, Wb); VWAIT(6); MX0(16, Wa);
                WX0(18, Wa); VWAIT(4); MX0(17, Wb);
                WX0(19, Wb); VWAIT(2); MX0(18, Wa);
                             VWAIT(0); MX0(19, Wb);
            } else {
                const unsigned short* bAy = h0hi + (size_t)wslot * PL
                                                 + (size_t)arow * HD + kb + kg8;
                short8 Ah[5], Al[5], Ay[5], Wa[6], Wb[6];
#define L1A(c) do { LDA16(Ah[(c)%5], bAh, (c)*64); LDA16(Al[(c)%5], bAl, (c)*64); \
                    LDA16(Ay[(c)%5], bAy, (c)*64); } while (0)
#define WR1(c, WB) do { WB[0] = LW(ckb + (c)); WB[1] = LW(32 + ckb + (c)); \
    WB[2] = LW(64 + ckb + (c)); WB[3] = LW(96 + ckb + (c)); \
    WB[4] = LW(128 + ckb + (c)); WB[5] = LW(160 + ckb + (c)); } while (0)
#define MF1(c, WB) do { \
    ar  = MFMA(Ah[(c)%5], WB[0], ar);  ar  = MFMA(Al[(c)%5], WB[0], ar);  \
    ar  = MFMA(Ay[(c)%5], WB[3], ar); \
    az  = MFMA(Ah[(c)%5], WB[1], az);  az  = MFMA(Al[(c)%5], WB[1], az);  \
    az  = MFMA(Ay[(c)%5], WB[4], az); \
    ahn = MFMA(Ah[(c)%5], WB[2], ahn); ahn = MFMA(Al[(c)%5], WB[2], ahn); \
    axn = MFMA(Ay[(c)%5], WB[5], axn); } while (0)
                WR1(0, Wa);
                L1A(0); L1A(1); L1A(2); L1A(3);
                WR1(1,  Wb); L1A(4);  VWAIT(12); MF1(0,  Wa);
                WR1(2,  Wa); L1A(5);  VWAIT(12); MF1(1,  Wb);
                WR1(3,  Wb); L1A(6);  VWAIT(12); MF1(2,  Wa);
                WR1(4,  Wa); L1A(7);  VWAIT(12); MF1(3,  Wb);
                WR1(5,  Wb); L1A(8);  VWAIT(12); MF1(4,  Wa);
                WR1(6,  Wa); L1A(9);  VWAIT(12); MF1(5,  Wb);
                WR1(7,  Wb); L1A(10); VWAIT(12); MF1(6,  Wa);
                WR1(8,  Wa); L1A(11); VWAIT(12); MF1(7,  Wb);
                WR1(9,  Wb); L1A(12); VWAIT(12); MF1(8,  Wa);
                WR1(10, Wa); L1A(13); VWAIT(12); MF1(9,  Wb);
                WR1(11, Wb); L1A(14); VWAIT(12); MF1(10, Wa);
                WR1(12, Wa); L1A(15); VWAIT(12); MF1(11, Wb);
                WR1(13, Wb); VWAIT(9); MF1(12, Wa);
                WR1(14, Wa); VWAIT(6); MF1(13, Wb);
                WR1(15, Wb); VWAIT(3); MF1(14, Wa);
                             VWAIT(0); MF1(15, Wb);
            }

            // ---- K-half combine in LDS; gates + h store on kh0 waves ----
            if (kh) {
                #pragma unroll
                for (int e = 0; e < 4; ++e) {
                    part[((0*4 + e) * 4 + mw) * 64 + lane] = ar[e];
                    part[((1*4 + e) * 4 + mw) * 64 + lane] = az[e];
                    part[((2*4 + e) * 4 + mw) * 64 + lane] = ahn[e];
                    part[((3*4 + e) * 4 + mw) * 64 + lane] = axn[e];
                }
            }
            __syncthreads();
            if (!kh) {
                unsigned short* hwhi = hhi + wslot * PL;
                unsigned short* hwlo = hlo + wslot * PL;
                #pragma unroll
                for (int e = 0; e < 4; ++e) {
                    const float arr = ar[e]  + part[((0*4 + e) * 4 + mw) * 64 + lane];
                    const float azz = az[e]  + part[((1*4 + e) * 4 + mw) * 64 + lane];
                    const float ahh = ahn[e] + part[((2*4 + e) * 4 + mw) * 64 + lane];
                    const float axx = axn[e] + part[((3*4 + e) * 4 + mw) * 64 + lane];
                    const int bat = (mw << 4) + ((lane >> 4) << 2) + e;
                    const size_t idx = (size_t)bat * HD + jg;
                    float r = sigm(arr + bias_r);
                    float z = sigm(azz + bias_z);
                    float n = tanh_fast(axx + bias_nx + r * (ahh + bias_nh));
                    float hnew = (1.0f - z) * n + z * hold[e];
                    hold[e] = hnew;
                    if (l15 < 8) {
                        unsigned short hi_ = f2bf(hnew);
                        cstore16(hwhi + idx, hi_);
                        cstore16(hwlo + idx, f2bf(hnew - bf2f((unsigned)hi_)));
                    }
                }
            }
        }

        // ---- flat global barrier (drain stores first) ----
        asm volatile("s_waitcnt vmcnt(0)" ::: "memory");
        __syncthreads();
        if (tid == 0) {
            atomicAdd(&arrive[(size_t)iter * FS], 1);
            int spins = 0;
            while (__hip_atomic_load(&arrive[(size_t)iter * FS],
                                     __ATOMIC_RELAXED, __HIP_MEMORY_SCOPE_AGENT) < NWG) {
                __builtin_amdgcn_s_sleep(1);
                if (++spins > (1 << 20)) break;   // fail loud, never hang
            }
        }
        __syncthreads();
    }

    // ---- deterministic FC tail (single WG, coherent reads) ----
    if (wg == 0) {
        const int fslot = (TSEQ - 1) & 1;
        const unsigned short* hf_hi = h1hi + (size_t)fslot * PL;
        const unsigned short* hf_lo = h1lo + (size_t)fslot * PL;
        if (tid < 256) {
            const int bat  = tid & 63;
            const int pidx = tid >> 6;
            const int k0   = pidx * (HD / 4);
            float s = 0.0f;
            for (int k = 0; k < HD / 4; ++k) {
                size_t idx = (size_t)bat * HD + k0 + k;
                s += (bf2f((unsigned)cload16(hf_hi + idx)) +
                      bf2f((unsigned)cload16(hf_lo + idx))) * wfc[k0 + k];
            }
            red[tid] = s;
        }
        __syncthreads();
        if (tid < 64)
            out[tid] = red[tid] + red[tid + 64] + red[tid + 128] + red[tid + 192] + bfc[0];
    }
}

extern "C" void kernel_launch(void* const* d_in, const int* in_sizes, int n_in,
                              void* d_out, int out_size, void* d_ws, size_t ws_size,
                              hipStream_t stream) {
    const float* x    = (const float*)d_in[0];
    const float* Wih0 = (const float*)d_in[1];
    const float* Whh0 = (const float*)d_in[2];
    const float* bih0 = (const float*)d_in[3];
    const float* bhh0 = (const float*)d_in[4];
    const float* Wih1 = (const float*)d_in[5];
    const float* Whh1 = (const float*)d_in[6];
    const float* bih1 = (const float*)d_in[7];
    const float* bhh1 = (const float*)d_in[8];
    const float* Wfc  = (const float*)d_in[9];
    const float* bfc  = (const float*)d_in[10];
    float* out = (float*)d_out;

    char* ws = (char*)d_ws;
    size_t off = 0;
    int* arrive = (int*)(ws + off);               off += (size_t)(TSEQ + 1) * FS * 4;
    unsigned short* h0hi = (unsigned short*)(ws + off); off += (size_t)2 * PL * 2;
    unsigned short* h0lo = (unsigned short*)(ws + off); off += (size_t)2 * PL * 2;
    unsigned short* h1hi = (unsigned short*)(ws + off); off += (size_t)2 * PL * 2;
    unsigned short* h1lo = (unsigned short*)(ws + off); off += (size_t)2 * PL * 2;
    size_t zero_bytes = off;
    unsigned short* wih0b = (unsigned short*)(ws + off); off += (size_t)3 * HD * IND * 2;
    unsigned short* whh0b = (unsigned short*)(ws + off); off += (size_t)3 * HD * HD * 2;
    unsigned short* wih1b = (unsigned short*)(ws + off); off += (size_t)3 * HD * HD * 2;
    unsigned short* whh1b = (unsigned short*)(ws + off); off += (size_t)3 * HD * HD * 2;
    if (off > ws_size) return;   // loud validation failure

    hipMemsetAsync(d_ws, 0, zero_bytes, stream);
    hipMemsetAsync(d_out, 0, (size_t)out_size * sizeof(float), stream);

    convert_w<<<512, 256, 0, stream>>>(Wih0, wih0b, 3 * HD * IND);
    convert_w<<<512, 256, 0, stream>>>(Whh0, whh0b, 3 * HD * HD);
    convert_w<<<512, 256, 0, stream>>>(Wih1, wih1b, 3 * HD * HD);
    convert_w<<<512, 256, 0, stream>>>(Whh1, whh1b, 3 * HD * HD);

    gru_main<<<NWG, 512, 0, stream>>>(x, wih0b, whh0b, wih1b, whh1b,
                                      bih0, bhh0, bih1, bhh1, Wfc, bfc,
                                      h0hi, h0lo, h1hi, h1lo, arrive, out);
}